// Round 4
// baseline (1361.061 us; speedup 1.0000x reference)
//
#include <hip/hip_runtime.h>
#include <math.h>

// Problem constants (fixed by setup_inputs): B=8 graphs, N=50000 nodes/graph,
// EPG=1e6 edges/graph, E=8e6, M=2048, num_passes=3.
#define GB    8
#define GN    50000
#define EPG   1000000
#define EDGES (GB*EPG)
#define NP    3

#define BW     4096           // src-bucket width (floats) -> 16KB LDS stage
#define NBUCK  13             // ceil(50000/4096); last bucket width 848
#define NBINS  (GB*NBUCK)     // 104
#define CAP    89088          // fixed recs capacity per bin (mean 81920, +26σ)
#define CPB    20             // chunk-blocks per bin -> 2080 accum blocks
#define STRIPE 4000           // edges per binning block
#define NQ     (STRIPE/4)     // 1000 quads
#define NBLKH  (EDGES/STRIPE) // 2000 binning blocks
#define BPG    (EPG/STRIPE)   // 250 blocks per graph
#define DSTMASK 0x7FFFFu      // dst_global fits 19 bits (BN=400000 < 2^19)

// ============================ fast path ============================
// Round-3 diagnosis: accum was latency-bound on the random 4B hin[src]
// gather (VALUBusy 3%, HBM 9%, occupancy 38%) -- the wave must WAIT on
// divergent L2 reads. Fix: role-swap the binning. Bin records by SRC
// bucket; accum stages the bin's 16KB h-window in LDS (gather -> ds_read),
// and the random side becomes a fire-and-forget global atomic on dst
// (no data dependency, never waited on).
// 1. z_k      : zero gcur/nsq + bufA/B/C (once; atomics accumulate into them)
// 2. fscatter : proven round-0 structure (62us), src-binned.
//               rec.x = (src_in_bucket << 19) | dst_global, rec.y = log1pf(w)
// 3. accum x3 : block (src-bucket, chunk): stage 16KB hin window coalesced,
//               per record ds_read + mul + unsafeAtomicAdd(hout[dst]).
// 4. nsq_k    : per-graph sum-of-squares of final h.
// 5. final_k  : telescoped norm + mask/normalize/pool.

__global__ void z_k(int* __restrict__ gcur, float* __restrict__ nsq,
                    float4* __restrict__ a, float4* __restrict__ b,
                    float4* __restrict__ c) {
  int i = blockIdx.x * 256 + threadIdx.x;
  float4 z = {0.f, 0.f, 0.f, 0.f};
  if (i < (GB * GN) / 4) { a[i] = z; b[i] = z; c[i] = z; }
  if (blockIdx.x == 0) {
    if (threadIdx.x < NBINS) gcur[threadIdx.x] = 0;
    if (threadIdx.x < GB) nsq[threadIdx.x] = 0.f;
  }
}

// Fused bin+rank+reserve+scatter (round-0 measured 62us; src-binned):
//  phase 1: per-edge rank within (block,bin) via LDS hist (ranks in regs)
//  phase 2: reserve per-bin offset via gcur atomic (13/block)
//  phase 3: re-read stripe (cache-resident) and write records:
//           pos = bin*CAP + lb[bin] + rank.
// After the kernel, gcur[bin] == bin's record count (used by accum).
__global__ __launch_bounds__(256) void fscatter_k(
    const int* __restrict__ src, const int* __restrict__ dst,
    const float* __restrict__ ew, int* __restrict__ gcur,
    uint2* __restrict__ recs) {
  __shared__ int lh[NBINS];
  __shared__ int lb[NBINS];
  if (threadIdx.x < NBINS) lh[threadIdx.x] = 0;
  __syncthreads();
  int blk = blockIdx.x;
  int s0 = blk * STRIPE;
  int g = blk / BPG;                  // stripe never crosses a graph
  int base = g * GN, gb = g * NBUCK;
  const int4* d4 = (const int4*)(dst + s0);
  const int4* s4 = (const int4*)(src + s0);
  const float4* w4 = (const float4*)(ew + s0);

  int rk[16];
#pragma unroll
  for (int u = 0; u < 4; ++u) {
    int q = threadIdx.x + 256 * u;
    if (q < NQ) {
      int4 s = s4[q];
      rk[4 * u + 0] = atomicAdd(&lh[gb + ((s.x - base) >> 12)], 1);
      rk[4 * u + 1] = atomicAdd(&lh[gb + ((s.y - base) >> 12)], 1);
      rk[4 * u + 2] = atomicAdd(&lh[gb + ((s.z - base) >> 12)], 1);
      rk[4 * u + 3] = atomicAdd(&lh[gb + ((s.w - base) >> 12)], 1);
    }
  }
  __syncthreads();
  if (threadIdx.x < NBINS) {
    int c = lh[threadIdx.x];
    lb[threadIdx.x] = c ? atomicAdd(&gcur[threadIdx.x], c) : 0;
  }
  __syncthreads();
#pragma unroll
  for (int u = 0; u < 4; ++u) {
    int q = threadIdx.x + 256 * u;
    if (q < NQ) {
      int4 d = d4[q]; int4 s = s4[q]; float4 w = w4[q];
      int dv[4] = {d.x, d.y, d.z, d.w};
      int sv[4] = {s.x, s.y, s.z, s.w};
      float wv[4] = {w.x, w.y, w.z, w.w};
#pragma unroll
      for (int k = 0; k < 4; ++k) {
        int sl = sv[k] - base;
        int bin = gb + (sl >> 12);
        int r = sl & (BW - 1);
        size_t pos = (size_t)bin * CAP + lb[bin] + rk[4 * u + k];
        recs[pos] = make_uint2(((unsigned)r << 19) | (unsigned)dv[k],
                               __float_as_uint(log1pf(wv[k])));
      }
    }
  }
}

// One (src-bucket, chunk) per 256-thread block. Stage the bin's 16KB hin
// window coalesced into LDS; per record: ds_read gather + mul + fire-and-
// forget global atomic to hout[dst]. No LDS accumulator, no epilogue.
__global__ __launch_bounds__(256) void accum_k(
    const uint2* __restrict__ recs, const int* __restrict__ cnt,
    const float* __restrict__ hin, float* __restrict__ hout) {
  __shared__ float sh[BW];
  int c = blockIdx.x;               // chunk [0,CPB)
  int bin = blockIdx.y;             // [0,NBINS)
  int g = bin / NBUCK, sb = bin - g * NBUCK;
  int sw = GN - sb * BW; if (sw > BW) sw = BW;     // 848 for bucket 12
  const float4* hp = (const float4*)(hin + (size_t)g * GN + (size_t)sb * BW);
  float4* sp = (float4*)sh;
  for (int i = threadIdx.x; i < sw / 4; i += 256) sp[i] = hp[i];

  int len = cnt[bin];
  int chunk = ((len + CPB - 1) / CPB + 1) & ~1;   // even chunk
  int lo = c * chunk;
  int hi = lo + chunk;
  if (lo > len) lo = len;
  if (hi > len) hi = len;
  const uint2* rb = recs + (size_t)bin * CAP;
  __syncthreads();
  int rem = hi - lo;                // lo even (CAP even, chunk even)
  if (rem < 0) rem = 0;
  int np = rem >> 1;                // uint4 count (2 recs each)
  const uint4* rp = (const uint4*)(rb + lo);
  int p = threadIdx.x;
  for (; p + 256 < np; p += 512) {
    uint4 r0 = rp[p];
    uint4 r1 = rp[p + 256];
    float a0 = sh[r0.x >> 19] * __uint_as_float(r0.y);
    float a1 = sh[r0.z >> 19] * __uint_as_float(r0.w);
    float a2 = sh[r1.x >> 19] * __uint_as_float(r1.y);
    float a3 = sh[r1.z >> 19] * __uint_as_float(r1.w);
    unsafeAtomicAdd(&hout[r0.x & DSTMASK], a0);
    unsafeAtomicAdd(&hout[r0.z & DSTMASK], a1);
    unsafeAtomicAdd(&hout[r1.x & DSTMASK], a2);
    unsafeAtomicAdd(&hout[r1.z & DSTMASK], a3);
  }
  if (p < np) {
    uint4 r0 = rp[p];
    unsafeAtomicAdd(&hout[r0.x & DSTMASK], sh[r0.x >> 19] * __uint_as_float(r0.y));
    unsafeAtomicAdd(&hout[r0.z & DSTMASK], sh[r0.z >> 19] * __uint_as_float(r0.w));
  }
  if ((rem & 1) && threadIdx.x == 0) {
    uint2 a = rb[hi - 1];
    unsafeAtomicAdd(&hout[a.x & DSTMASK], sh[a.x >> 19] * __uint_as_float(a.y));
  }
}

// Per-graph sum of squares of h (device-wide, float4-vectorized).
__global__ void nsq_k(const float4* __restrict__ h4, float* __restrict__ nsq) {
  __shared__ float sm[GB];
  if (threadIdx.x < GB) sm[threadIdx.x] = 0.f;
  __syncthreads();
  int n4 = blockIdx.x * 256 + threadIdx.x;
  if (n4 < (GB * GN) / 4) {
    float4 t = h4[n4];
    int g = (n4 * 4) / GN;
    atomicAdd(&sm[g], t.x * t.x + t.y * t.y + t.z * t.z + t.w * t.w);
  }
  __syncthreads();
  if (threadIdx.x < GB && sm[threadIdx.x] != 0.f)
    unsafeAtomicAdd(&nsq[threadIdx.x], sm[threadIdx.x]);
}

// ============================ v1 fallback ============================

__global__ void init_k(const float* __restrict__ x, float* __restrict__ h_cur,
                       float* __restrict__ h_next, float* __restrict__ norms,
                       int BN, int n_norms) {
  int i = blockIdx.x * blockDim.x + threadIdx.x;
  int stride = gridDim.x * blockDim.x;
  for (int j = i; j < BN; j += stride) { h_cur[j] = x[j]; h_next[j] = 0.f; }
  if (i < n_norms) norms[i] = 0.f;
}

__global__ void edge_k(const int* __restrict__ src, const int* __restrict__ dst,
                       const float* __restrict__ ew, const float* __restrict__ h_in,
                       float* __restrict__ h_out, int E4, int E) {
  int i = blockIdx.x * blockDim.x + threadIdx.x;
  int stride = gridDim.x * blockDim.x;
  const int4* s4 = (const int4*)src;
  const int4* d4 = (const int4*)dst;
  const float4* w4 = (const float4*)ew;
  for (int j = i; j < E4; j += stride) {
    int4 s = s4[j]; int4 d = d4[j]; float4 w = w4[j];
    unsafeAtomicAdd(&h_out[d.x], h_in[s.x] * log1pf(w.x));
    unsafeAtomicAdd(&h_out[d.y], h_in[s.y] * log1pf(w.y));
    unsafeAtomicAdd(&h_out[d.z], h_in[s.z] * log1pf(w.z));
    unsafeAtomicAdd(&h_out[d.w], h_in[s.w] * log1pf(w.w));
  }
  for (int j = E4 * 4 + i; j < E; j += stride)
    unsafeAtomicAdd(&h_out[dst[j]], h_in[src[j]] * log1pf(ew[j]));
}

__global__ void norm_k(const float* __restrict__ h, float* __restrict__ norms, int N) {
  int g = blockIdx.y;
  const float* hg = h + (size_t)g * N;
  float s = 0.f;
  for (int j = blockIdx.x * blockDim.x + threadIdx.x; j < N; j += gridDim.x * blockDim.x) {
    float v = hg[j]; s += v * v;
  }
  __shared__ float sm[4];
  for (int o = 32; o > 0; o >>= 1) s += __shfl_down(s, o, 64);
  if ((threadIdx.x & 63) == 0) sm[threadIdx.x >> 6] = s;
  __syncthreads();
  if (threadIdx.x == 0) {
    float t = 0.f;
    for (int w = 0; w < (int)(blockDim.x >> 6); ++w) t += sm[w];
    unsafeAtomicAdd(&norms[g], t);
  }
}

__global__ void scale_k(const float* __restrict__ norms, float* __restrict__ h_next,
                        float* __restrict__ h_cur, int N) {
  int g = blockIdx.y;
  float inv = 1.0f / sqrtf(norms[g]);
  size_t off = (size_t)g * N;
  for (int j = blockIdx.x * blockDim.x + threadIdx.x; j < N; j += gridDim.x * blockDim.x) {
    h_cur[off + j] = h_next[off + j] * inv;
    h_next[off + j] = 0.f;
  }
}

// ============================ shared epilogue ============================
__device__ __forceinline__ float blk_red(float t, float* sm, int nw) {
  for (int o = 32; o > 0; o >>= 1) t += __shfl_down(t, o, 64);
  if ((threadIdx.x & 63) == 0) sm[threadIdx.x >> 6] = t;
  __syncthreads();
  float r = 0.f;
  for (int w = 0; w < nw; ++w) r += sm[w];
  __syncthreads();
  return r;
}

__global__ void final_k(const float* __restrict__ h, const float* __restrict__ nsq,
                        const int* __restrict__ dm,
                        const float* __restrict__ fc_w, const float* __restrict__ fc_b,
                        float* __restrict__ out, int N, int M) {
  extern __shared__ float v[];
  __shared__ float sm[16];
  int b = blockIdx.x;
  int nw = blockDim.x >> 6;
  float inv = nsq ? 1.0f / sqrtf(nsq[b]) : 1.0f;
  const float* hb = h + (size_t)b * N;
  for (int m = threadIdx.x; m < M; m += blockDim.x) v[m] = hb[dm[m]] * inv;
  __syncthreads();

  float cnt = 0.f, sum = 0.f;
  for (int m = threadIdx.x; m < M; m += blockDim.x) {
    float xv = v[m];
    if (xv != 0.f) { cnt += 1.f; sum += xv; }
  }
  float totalSum = blk_red(sum, sm, nw);
  float totalCnt = blk_red(cnt, sm, nw);
  float mean = totalCnt > 0.f ? totalSum / totalCnt : 0.f;

  float ssq = 0.f;
  for (int m = threadIdx.x; m < M; m += blockDim.x) {
    float xv = v[m];
    if (xv != 0.f) { float d = xv - mean; ssq += d * d; }
  }
  float totalSsq = blk_red(ssq, sm, nw);

  float denom = totalCnt - 1.f;
  if (denom < 1.f) denom = 1.f;
  float stdv = sqrtf(totalSsq / denom) + 1e-5f;

  float ps = 0.f;
  for (int m = threadIdx.x; m < M; m += blockDim.x) {
    float xv = v[m];
    if (xv != 0.f) ps += (xv - mean) / stdv;
  }
  float pooled = blk_red(ps, sm, nw) / (float)M;
  if (threadIdx.x == 0) {
    float o = pooled * fc_w[0] + fc_b[0];
    out[b] = o > 0.f ? o : 0.f;
  }
}

extern "C" void kernel_launch(void* const* d_in, const int* in_sizes, int n_in,
                              void* d_out, int out_size, void* d_ws, size_t ws_size,
                              hipStream_t stream) {
  const float* x    = (const float*)d_in[0];
  const float* ew   = (const float*)d_in[1];
  const int*   src  = (const int*)d_in[2];
  const int*   dst  = (const int*)d_in[3];
  const int*   dm   = (const int*)d_in[4];
  const float* fc_w = (const float*)d_in[5];
  const float* fc_b = (const float*)d_in[6];

  const int BN = in_sizes[0];   // 400000
  const int E  = in_sizes[1];   // 8000000
  const int M  = in_sizes[4];   // 2048
  const int N  = BN / GB;

  const bool shapes_ok = (BN == GB * GN) && (E == EDGES);

  // ---- layout (fixed-capacity recs; REQ ~ 79 MB <= verified floor) ----
  const size_t recs_b = (size_t)NBINS * CAP * 8;   // 74,121,216
  const size_t buf_b  = (size_t)BN * 4;            // 1,600,000
  const size_t misc_b = 4096;
  const size_t REQ = recs_b + 3 * buf_b + misc_b;

  if (shapes_ok && ws_size >= REQ) {
    uint2* recs = (uint2*)d_ws;
    float* bufA = (float*)((char*)d_ws + recs_b);
    float* bufB = bufA + BN;
    float* bufC = bufB + BN;
    int*   gcur = (int*)(bufC + BN);               // [NBINS]; == counts after fscatter
    float* nsq  = (float*)(gcur + NBINS + 8);      // [GB]

    z_k<<<(BN / 4 + 255) / 256, 256, 0, stream>>>(gcur, nsq, (float4*)bufA,
                                                  (float4*)bufB, (float4*)bufC);
    fscatter_k<<<NBLKH, 256, 0, stream>>>(src, dst, ew, gcur, recs);

    dim3 agrid(CPB, NBINS);
    accum_k<<<agrid, 256, 0, stream>>>(recs, gcur, x, bufA);
    accum_k<<<agrid, 256, 0, stream>>>(recs, gcur, bufA, bufB);
    accum_k<<<agrid, 256, 0, stream>>>(recs, gcur, bufB, bufC);

    nsq_k<<<(BN / 4 + 255) / 256, 256, 0, stream>>>((const float4*)bufC, nsq);
    final_k<<<GB, 512, M * sizeof(float), stream>>>(bufC, nsq, dm, fc_w, fc_b,
                                                    (float*)d_out, N, M);
    return;
  }

  // ---- v1 fallback ----
  float* h_cur  = (float*)d_ws;
  float* h_next = h_cur + BN;
  float* norms  = h_next + BN;
  const int threads = 256;
  init_k<<<(BN + threads - 1) / threads, threads, 0, stream>>>(x, h_cur, h_next,
                                                               norms, BN, NP * GB);
  int E4 = E / 4;
  int edgeBlocks = (E4 + threads - 1) / threads;
  dim3 ngrid((N + threads * 8 - 1) / (threads * 8), GB);
  for (int p = 0; p < NP; ++p) {
    edge_k<<<edgeBlocks, threads, 0, stream>>>(src, dst, ew, h_cur, h_next, E4, E);
    norm_k<<<ngrid, threads, 0, stream>>>(h_next, norms + p * GB, N);
    scale_k<<<ngrid, threads, 0, stream>>>(norms + p * GB, h_next, h_cur, N);
  }
  final_k<<<GB, 256, M * sizeof(float), stream>>>(h_cur, nullptr, dm, fc_w, fc_b,
                                                  (float*)d_out, N, M);
}

// Round 5
// 362.071 us; speedup vs baseline: 3.7591x; 3.7591x over previous
//
#include <hip/hip_runtime.h>
#include <math.h>

// Problem constants (fixed by setup_inputs): B=8 graphs, N=50000 nodes/graph,
// EPG=1e6 edges/graph, E=8e6, M=2048, num_passes=3.
#define GB    8
#define GN    50000
#define EPG   1000000
#define EDGES (GB*EPG)
#define NP    3

#define BW     4096           // dst-bucket width (floats) -> 16KB LDS accum
#define NBUCK  13             // ceil(50000/4096); last bucket width 848
#define NBINS  (GB*NBUCK)     // 104
#define CAP    89088          // fixed recs capacity per bin (mean 81920, +26σ)
#define CPB    20             // chunk-blocks per bin -> 2080 accum blocks (8/CU)
#define STRIPE 4000           // edges per binning block
#define NQ     (STRIPE/4)     // 1000 quads
#define NBLKH  (EDGES/STRIPE) // 2000 binning blocks
#define BPG    (EPG/STRIPE)   // 250 blocks per graph
#define SRCMASK 0x7FFFFu      // src fits 19 bits (BN=400000 < 2^19)

// ============================ fast path ============================
// Ledger: dst-binned accum ~75-86us across {global gather, LDS-staged gather,
// batch-8 MLP} variants -- all at ~4 blocks/CU. Round-4 proved random global
// atomics are a 2e10/s wall (NOT viable). Round 5 isolates the last untested
// axis: per-CU wave concurrency. CPB 10->20 => 2080 blocks = 8 blocks/CU =
// 32 waves/CU (wave-limited max). Everything else = proven-best round-0/2.
// 1. z_k      : zero gcur/nsq + bufA/B/C (once)
// 2. fscatter : round-0 proven version (62us): 13-dst-bin rank+reserve+scatter
//               rec.x = (dst_in_bucket << 19) | src_global, rec.y = log1pf(w)
// 3. accum x3 : one (bin,chunk) per 256-thread block; 2x uint4/iter; LDS
//               accumulate; zero-skip coalesced-atomic epilogue into hout.
// 4. nsq_k    : per-graph sum-of-squares of final h.
// 5. final_k  : telescoped norm + mask/normalize/pool.

__global__ void z_k(int* __restrict__ gcur, float* __restrict__ nsq,
                    float4* __restrict__ a, float4* __restrict__ b,
                    float4* __restrict__ c) {
  int i = blockIdx.x * 256 + threadIdx.x;
  float4 z = {0.f, 0.f, 0.f, 0.f};
  if (i < (GB * GN) / 4) { a[i] = z; b[i] = z; c[i] = z; }
  if (blockIdx.x == 0) {
    if (threadIdx.x < NBINS) gcur[threadIdx.x] = 0;
    if (threadIdx.x < GB) nsq[threadIdx.x] = 0.f;
  }
}

// Fused bin+rank+reserve+scatter (round-0 measured 62us; dst-binned):
//  phase 1: per-edge rank within (block,bin) via LDS hist (ranks in regs)
//  phase 2: reserve per-bin offset via gcur atomic (13/block)
//  phase 3: re-read stripe (cache-resident) and write records:
//           pos = bin*CAP + lb[bin] + rank.
// After the kernel, gcur[bin] == bin's record count (used by accum).
__global__ __launch_bounds__(256) void fscatter_k(
    const int* __restrict__ src, const int* __restrict__ dst,
    const float* __restrict__ ew, int* __restrict__ gcur,
    uint2* __restrict__ recs) {
  __shared__ int lh[NBINS];
  __shared__ int lb[NBINS];
  if (threadIdx.x < NBINS) lh[threadIdx.x] = 0;
  __syncthreads();
  int blk = blockIdx.x;
  int s0 = blk * STRIPE;
  int g = blk / BPG;                  // stripe never crosses a graph
  int base = g * GN, gb = g * NBUCK;
  const int4* d4 = (const int4*)(dst + s0);
  const int4* s4 = (const int4*)(src + s0);
  const float4* w4 = (const float4*)(ew + s0);

  int rk[16];
#pragma unroll
  for (int u = 0; u < 4; ++u) {
    int q = threadIdx.x + 256 * u;
    if (q < NQ) {
      int4 d = d4[q];
      rk[4 * u + 0] = atomicAdd(&lh[gb + ((d.x - base) >> 12)], 1);
      rk[4 * u + 1] = atomicAdd(&lh[gb + ((d.y - base) >> 12)], 1);
      rk[4 * u + 2] = atomicAdd(&lh[gb + ((d.z - base) >> 12)], 1);
      rk[4 * u + 3] = atomicAdd(&lh[gb + ((d.w - base) >> 12)], 1);
    }
  }
  __syncthreads();
  if (threadIdx.x < NBINS) {
    int c = lh[threadIdx.x];
    lb[threadIdx.x] = c ? atomicAdd(&gcur[threadIdx.x], c) : 0;
  }
  __syncthreads();
#pragma unroll
  for (int u = 0; u < 4; ++u) {
    int q = threadIdx.x + 256 * u;
    if (q < NQ) {
      int4 d = d4[q]; int4 s = s4[q]; float4 w = w4[q];
      int dv[4] = {d.x, d.y, d.z, d.w};
      int sv[4] = {s.x, s.y, s.z, s.w};
      float wv[4] = {w.x, w.y, w.z, w.w};
#pragma unroll
      for (int k = 0; k < 4; ++k) {
        int dl = dv[k] - base;
        int bin = gb + (dl >> 12);
        int r = dl & (BW - 1);
        size_t pos = (size_t)bin * CAP + lb[bin] + rk[4 * u + k];
        recs[pos] = make_uint2(((unsigned)r << 19) | (unsigned)sv[k],
                               __float_as_uint(log1pf(wv[k])));
      }
    }
  }
}

// One (bin, chunk) per 256-thread block: LDS-accumulate this bin's edges;
// 2x uint4/iter. Epilogue: zero-skip coalesced atomic add into hout
// (pre-zeroed). 2080 blocks -> 8 blocks/CU -> 32 waves/CU.
__global__ __launch_bounds__(256) void accum_k(
    const uint2* __restrict__ recs, const int* __restrict__ cnt,
    const float* __restrict__ hin, float* __restrict__ hout) {
  __shared__ float acc[BW];
  int c = blockIdx.x;               // chunk [0,CPB)
  int bin = blockIdx.y;             // [0,NBINS)
  float4 z = {0.f, 0.f, 0.f, 0.f};
  float4* a4 = (float4*)acc;
  for (int i = threadIdx.x; i < BW / 4; i += 256) a4[i] = z;
  int len = cnt[bin];
  int chunk = ((len + CPB - 1) / CPB + 1) & ~1;   // even chunk
  int lo = c * chunk;
  int hi = lo + chunk;
  if (lo > len) lo = len;
  if (hi > len) hi = len;
  const uint2* rb = recs + (size_t)bin * CAP;
  __syncthreads();
  int rem = hi - lo;                // lo even (CAP even, chunk even)
  if (rem < 0) rem = 0;
  int np = rem >> 1;                // uint4 count (2 recs each)
  const uint4* rp = (const uint4*)(rb + lo);
  int p = threadIdx.x;
  for (; p + 256 < np; p += 512) {
    uint4 r0 = rp[p];
    uint4 r1 = rp[p + 256];
    float a0 = hin[r0.x & SRCMASK] * __uint_as_float(r0.y);
    float a1 = hin[r0.z & SRCMASK] * __uint_as_float(r0.w);
    float a2 = hin[r1.x & SRCMASK] * __uint_as_float(r1.y);
    float a3 = hin[r1.z & SRCMASK] * __uint_as_float(r1.w);
    atomicAdd(&acc[r0.x >> 19], a0);
    atomicAdd(&acc[r0.z >> 19], a1);
    atomicAdd(&acc[r1.x >> 19], a2);
    atomicAdd(&acc[r1.z >> 19], a3);
  }
  if (p < np) {
    uint4 r0 = rp[p];
    atomicAdd(&acc[r0.x >> 19], hin[r0.x & SRCMASK] * __uint_as_float(r0.y));
    atomicAdd(&acc[r0.z >> 19], hin[r0.z & SRCMASK] * __uint_as_float(r0.w));
  }
  if ((rem & 1) && threadIdx.x == 0) {
    uint2 a = rb[hi - 1];
    atomicAdd(&acc[a.x >> 19], hin[a.x & SRCMASK] * __uint_as_float(a.y));
  }
  __syncthreads();
  int g = bin / NBUCK, bucket = bin - g * NBUCK;
  int sw = GN - bucket * BW; if (sw > BW) sw = BW;   // 848 for bucket 12
  float* ho = hout + (size_t)g * GN + (size_t)bucket * BW;
  for (int i = threadIdx.x; i < sw; i += 256) {
    float v = acc[i];
    if (v != 0.f) unsafeAtomicAdd(&ho[i], v);
  }
}

// Per-graph sum of squares of h (device-wide, float4-vectorized).
__global__ void nsq_k(const float4* __restrict__ h4, float* __restrict__ nsq) {
  __shared__ float sm[GB];
  if (threadIdx.x < GB) sm[threadIdx.x] = 0.f;
  __syncthreads();
  int n4 = blockIdx.x * 256 + threadIdx.x;
  if (n4 < (GB * GN) / 4) {
    float4 t = h4[n4];
    int g = (n4 * 4) / GN;
    atomicAdd(&sm[g], t.x * t.x + t.y * t.y + t.z * t.z + t.w * t.w);
  }
  __syncthreads();
  if (threadIdx.x < GB && sm[threadIdx.x] != 0.f)
    unsafeAtomicAdd(&nsq[threadIdx.x], sm[threadIdx.x]);
}

// ============================ v1 fallback ============================

__global__ void init_k(const float* __restrict__ x, float* __restrict__ h_cur,
                       float* __restrict__ h_next, float* __restrict__ norms,
                       int BN, int n_norms) {
  int i = blockIdx.x * blockDim.x + threadIdx.x;
  int stride = gridDim.x * blockDim.x;
  for (int j = i; j < BN; j += stride) { h_cur[j] = x[j]; h_next[j] = 0.f; }
  if (i < n_norms) norms[i] = 0.f;
}

__global__ void edge_k(const int* __restrict__ src, const int* __restrict__ dst,
                       const float* __restrict__ ew, const float* __restrict__ h_in,
                       float* __restrict__ h_out, int E4, int E) {
  int i = blockIdx.x * blockDim.x + threadIdx.x;
  int stride = gridDim.x * blockDim.x;
  const int4* s4 = (const int4*)src;
  const int4* d4 = (const int4*)dst;
  const float4* w4 = (const float4*)ew;
  for (int j = i; j < E4; j += stride) {
    int4 s = s4[j]; int4 d = d4[j]; float4 w = w4[j];
    unsafeAtomicAdd(&h_out[d.x], h_in[s.x] * log1pf(w.x));
    unsafeAtomicAdd(&h_out[d.y], h_in[s.y] * log1pf(w.y));
    unsafeAtomicAdd(&h_out[d.z], h_in[s.z] * log1pf(w.z));
    unsafeAtomicAdd(&h_out[d.w], h_in[s.w] * log1pf(w.w));
  }
  for (int j = E4 * 4 + i; j < E; j += stride)
    unsafeAtomicAdd(&h_out[dst[j]], h_in[src[j]] * log1pf(ew[j]));
}

__global__ void norm_k(const float* __restrict__ h, float* __restrict__ norms, int N) {
  int g = blockIdx.y;
  const float* hg = h + (size_t)g * N;
  float s = 0.f;
  for (int j = blockIdx.x * blockDim.x + threadIdx.x; j < N; j += gridDim.x * blockDim.x) {
    float v = hg[j]; s += v * v;
  }
  __shared__ float sm[4];
  for (int o = 32; o > 0; o >>= 1) s += __shfl_down(s, o, 64);
  if ((threadIdx.x & 63) == 0) sm[threadIdx.x >> 6] = s;
  __syncthreads();
  if (threadIdx.x == 0) {
    float t = 0.f;
    for (int w = 0; w < (int)(blockDim.x >> 6); ++w) t += sm[w];
    unsafeAtomicAdd(&norms[g], t);
  }
}

__global__ void scale_k(const float* __restrict__ norms, float* __restrict__ h_next,
                        float* __restrict__ h_cur, int N) {
  int g = blockIdx.y;
  float inv = 1.0f / sqrtf(norms[g]);
  size_t off = (size_t)g * N;
  for (int j = blockIdx.x * blockDim.x + threadIdx.x; j < N; j += gridDim.x * blockDim.x) {
    h_cur[off + j] = h_next[off + j] * inv;
    h_next[off + j] = 0.f;
  }
}

// ============================ shared epilogue ============================
__device__ __forceinline__ float blk_red(float t, float* sm, int nw) {
  for (int o = 32; o > 0; o >>= 1) t += __shfl_down(t, o, 64);
  if ((threadIdx.x & 63) == 0) sm[threadIdx.x >> 6] = t;
  __syncthreads();
  float r = 0.f;
  for (int w = 0; w < nw; ++w) r += sm[w];
  __syncthreads();
  return r;
}

__global__ void final_k(const float* __restrict__ h, const float* __restrict__ nsq,
                        const int* __restrict__ dm,
                        const float* __restrict__ fc_w, const float* __restrict__ fc_b,
                        float* __restrict__ out, int N, int M) {
  extern __shared__ float v[];
  __shared__ float sm[16];
  int b = blockIdx.x;
  int nw = blockDim.x >> 6;
  float inv = nsq ? 1.0f / sqrtf(nsq[b]) : 1.0f;
  const float* hb = h + (size_t)b * N;
  for (int m = threadIdx.x; m < M; m += blockDim.x) v[m] = hb[dm[m]] * inv;
  __syncthreads();

  float cnt = 0.f, sum = 0.f;
  for (int m = threadIdx.x; m < M; m += blockDim.x) {
    float xv = v[m];
    if (xv != 0.f) { cnt += 1.f; sum += xv; }
  }
  float totalSum = blk_red(sum, sm, nw);
  float totalCnt = blk_red(cnt, sm, nw);
  float mean = totalCnt > 0.f ? totalSum / totalCnt : 0.f;

  float ssq = 0.f;
  for (int m = threadIdx.x; m < M; m += blockDim.x) {
    float xv = v[m];
    if (xv != 0.f) { float d = xv - mean; ssq += d * d; }
  }
  float totalSsq = blk_red(ssq, sm, nw);

  float denom = totalCnt - 1.f;
  if (denom < 1.f) denom = 1.f;
  float stdv = sqrtf(totalSsq / denom) + 1e-5f;

  float ps = 0.f;
  for (int m = threadIdx.x; m < M; m += blockDim.x) {
    float xv = v[m];
    if (xv != 0.f) ps += (xv - mean) / stdv;
  }
  float pooled = blk_red(ps, sm, nw) / (float)M;
  if (threadIdx.x == 0) {
    float o = pooled * fc_w[0] + fc_b[0];
    out[b] = o > 0.f ? o : 0.f;
  }
}

extern "C" void kernel_launch(void* const* d_in, const int* in_sizes, int n_in,
                              void* d_out, int out_size, void* d_ws, size_t ws_size,
                              hipStream_t stream) {
  const float* x    = (const float*)d_in[0];
  const float* ew   = (const float*)d_in[1];
  const int*   src  = (const int*)d_in[2];
  const int*   dst  = (const int*)d_in[3];
  const int*   dm   = (const int*)d_in[4];
  const float* fc_w = (const float*)d_in[5];
  const float* fc_b = (const float*)d_in[6];

  const int BN = in_sizes[0];   // 400000
  const int E  = in_sizes[1];   // 8000000
  const int M  = in_sizes[4];   // 2048
  const int N  = BN / GB;

  const bool shapes_ok = (BN == GB * GN) && (E == EDGES);

  // ---- layout (fixed-capacity recs; REQ ~ 79 MB <= verified floor) ----
  const size_t recs_b = (size_t)NBINS * CAP * 8;   // 74,121,216
  const size_t buf_b  = (size_t)BN * 4;            // 1,600,000
  const size_t misc_b = 4096;
  const size_t REQ = recs_b + 3 * buf_b + misc_b;

  if (shapes_ok && ws_size >= REQ) {
    uint2* recs = (uint2*)d_ws;
    float* bufA = (float*)((char*)d_ws + recs_b);
    float* bufB = bufA + BN;
    float* bufC = bufB + BN;
    int*   gcur = (int*)(bufC + BN);               // [NBINS]; == counts after fscatter
    float* nsq  = (float*)(gcur + NBINS + 8);      // [GB]

    z_k<<<(BN / 4 + 255) / 256, 256, 0, stream>>>(gcur, nsq, (float4*)bufA,
                                                  (float4*)bufB, (float4*)bufC);
    fscatter_k<<<NBLKH, 256, 0, stream>>>(src, dst, ew, gcur, recs);

    dim3 agrid(CPB, NBINS);
    accum_k<<<agrid, 256, 0, stream>>>(recs, gcur, x, bufA);
    accum_k<<<agrid, 256, 0, stream>>>(recs, gcur, bufA, bufB);
    accum_k<<<agrid, 256, 0, stream>>>(recs, gcur, bufB, bufC);

    nsq_k<<<(BN / 4 + 255) / 256, 256, 0, stream>>>((const float4*)bufC, nsq);
    final_k<<<GB, 512, M * sizeof(float), stream>>>(bufC, nsq, dm, fc_w, fc_b,
                                                    (float*)d_out, N, M);
    return;
  }

  // ---- v1 fallback ----
  float* h_cur  = (float*)d_ws;
  float* h_next = h_cur + BN;
  float* norms  = h_next + BN;
  const int threads = 256;
  init_k<<<(BN + threads - 1) / threads, threads, 0, stream>>>(x, h_cur, h_next,
                                                               norms, BN, NP * GB);
  int E4 = E / 4;
  int edgeBlocks = (E4 + threads - 1) / threads;
  dim3 ngrid((N + threads * 8 - 1) / (threads * 8), GB);
  for (int p = 0; p < NP; ++p) {
    edge_k<<<edgeBlocks, threads, 0, stream>>>(src, dst, ew, h_cur, h_next, E4, E);
    norm_k<<<ngrid, threads, 0, stream>>>(h_next, norms + p * GB, N);
    scale_k<<<ngrid, threads, 0, stream>>>(norms + p * GB, h_next, h_cur, N);
  }
  final_k<<<GB, 256, M * sizeof(float), stream>>>(h_cur, nullptr, dm, fc_w, fc_b,
                                                  (float*)d_out, N, M);
}